// Round 9
// baseline (169.708 us; speedup 1.0000x reference)
//
#include <hip/hip_runtime.h>
#include <stdint.h>

#define SPARSE_D 41
#define SPARSE_H 1600
#define SPARSE_W 1408
#define BN_EPS 0.001f

static constexpr int NYB = SPARSE_H / 2;          // 800
static constexpr int NBUCKET = SPARSE_D * NYB;    // 32,800
static constexpr int NBS = (NBUCKET + 255) / 256; // 129 scan blocks
static constexpr int PCAP = 12;                   // max non-self pairs per voxel (lambda~0.056)

// Spatial renumbering: voxels sorted by bucket (z*NYB + y/2) so adjacent threads
// are spatial neighbors -> gather instructions touch few distinct cache lines.
// bent2 bucket line: word0 = count, words 1..31 = entries (NEW idx).
// entry: [29]=y&1, [28:18]=x (11b), [17:0]=new idx ; pair: [22:18]=k, [17:0]=new idx
// vo[v] = (packed coords, original index)

// ---------------- pass 1: count per bucket, remember (bucket,slot) ----------------
__global__ void k_insert(const int* __restrict__ coords, uint32_t* __restrict__ cnts,
                         uint32_t* __restrict__ slotarr, int N) {
    int n = blockIdx.x * blockDim.x + threadIdx.x;
    if (n >= N) return;
    int4 c4 = ((const int4*)coords)[n];
    int z = c4.y, y = c4.z;
    int b = z * NYB + (y >> 1);
    int slot = (int)atomicAdd(&cnts[b], 1u) + 1;
    slotarr[n] = ((uint32_t)b << 6) | (uint32_t)min(slot, 32);   // 32 = overflow marker
}

// ---- pass 2 (single dispatch): per-block redundant global prefix + in-block scan ----
// Block i sums cnts[0..i*256) itself (coalesced, L2-hot; <=128 iters over 256 thr),
// so no inter-block handoff is needed. Also writes bent2 word0 (count).
__global__ void k_scan1(const uint32_t* __restrict__ cnts, uint32_t* __restrict__ bent2,
                        int* __restrict__ base, int NB, int nbs) {
    __shared__ int ws[4];
    __shared__ int wsum[4];
    __shared__ int s_pref;
    int tid = threadIdx.x, lane = tid & 63, wid = tid >> 6;
    int b0 = (int)blockIdx.x * 256;

    // global prefix over buckets [0, b0)
    int ps = 0;
    for (int j = tid; j < b0; j += 256) ps += min((int)cnts[j], 31);
    #pragma unroll
    for (int off = 32; off; off >>= 1) ps += __shfl_xor(ps, off);
    if (lane == 0) ws[wid] = ps;
    __syncthreads();
    if (tid == 0) s_pref = ws[0] + ws[1] + ws[2] + ws[3];

    // local tile: load count, write bent2 word0, clamp
    int b = b0 + tid;
    int c = 0;
    if (b < NB) {
        uint32_t cv = cnts[b];
        bent2[(size_t)b * 32] = cv;
        c = min((int)cv, 31);
    }
    // wave inclusive scan
    int inc = c;
    #pragma unroll
    for (int off = 1; off < 64; off <<= 1) {
        int t = __shfl_up(inc, off);
        if (lane >= off) inc += t;
    }
    if (lane == 63) wsum[wid] = inc;
    __syncthreads();
    if (tid == 0) {
        int r = 0;
        #pragma unroll
        for (int w = 0; w < 4; ++w) { int t = wsum[w]; wsum[w] = r; r += t; }
    }
    __syncthreads();
    int excl = s_pref + wsum[wid] + inc - c;
    if (b < NB) base[b] = excl;                       // coalesced
    if ((int)blockIdx.x == nbs - 1 && tid == 255) {   // b >= NB here -> c = 0, excl = total
        base[NB] = excl;
        base[NB + 1] = 0;                             // overflow counter
    }
}

// ---------------- pass 3: build permutation + bucket entries + sorted feat ----------------
__global__ void k_permute(const int* __restrict__ coords, const float* __restrict__ feat,
                          const uint32_t* __restrict__ slotarr, int* __restrict__ base,
                          uint32_t* __restrict__ bent2, uint2* __restrict__ vo,
                          float* __restrict__ featp, int NB, int N) {
    int n = blockIdx.x * blockDim.x + threadIdx.x;
    if (n >= N) return;
    uint32_t sv = slotarr[n];
    int b = (int)(sv >> 6), s = (int)(sv & 63u);
    int4 c4 = ((const int4*)coords)[n];
    int z = c4.y, y = c4.z, x = c4.w;
    int v;
    if (s <= 31) {
        v = base[b] + s - 1;
        bent2[(size_t)b * 32 + s] = ((uint32_t)(y & 1) << 29) | ((uint32_t)x << 18) | (uint32_t)v;
    } else {
        v = base[NB] + atomicAdd((uint32_t*)&base[NB + 1], 1u);   // not in bucket (matches old drop)
    }
    uint32_t cz = ((uint32_t)z << 22) | ((uint32_t)y << 11) | (uint32_t)x;
    vo[v] = make_uint2(cz, (uint32_t)n);              // one 8B scattered store
    float f0 = feat[n * 3 + 0], f1 = feat[n * 3 + 1], f2 = feat[n * 3 + 2];
    ((float4*)featp)[v] = make_float4(f0, f1, f2, 0.f);
}

// XCD-chunked bijective block swizzle (adjacent blocks -> same XCD's L2)
__device__ __forceinline__ int xcd_swz(int o, int nwg) {
    int q = nwg >> 3, r = nwg & 7;
    int x = o & 7, i = o >> 3;
    return (x < r ? x * (q + 1) : r * (q + 1) + (x - r) * q) + i;
}

// ---- stats epilogue: wave shuffle reduce -> LDS -> per-block partials ----
__device__ __forceinline__ void stats_epilogue(const float acc[16],
                                               float* __restrict__ partials, int blk,
                                               float (*sred)[32]) {
    int lid = threadIdx.x & 63;
    int wid = threadIdx.x >> 6;
    #pragma unroll
    for (int d = 0; d < 16; ++d) {
        float v = acc[d];
        float v2 = v * v;
        #pragma unroll
        for (int off = 32; off; off >>= 1) {
            v += __shfl_xor(v, off);
            v2 += __shfl_xor(v2, off);
        }
        if (lid == 0) { sred[wid][d] = v; sred[wid][16 + d] = v2; }
    }
    __syncthreads();
    if (threadIdx.x < 32)
        partials[(size_t)blk * 32 + threadIdx.x] =
            sred[0][threadIdx.x] + sred[1][threadIdx.x] +
            sred[2][threadIdx.x] + sred[3][threadIdx.x];
}

// ------ fused: build pairs + conv1 (C=3->16, LDS weights) in SORTED order ------
__global__ void k_build_conv1(const uint2* __restrict__ vo, const uint32_t* __restrict__ bent2,
                              const float* __restrict__ featp, const float* __restrict__ w1,
                              int* __restrict__ pcnt, uint32_t* __restrict__ pairs,
                              float* __restrict__ h1, float* __restrict__ partials, int N) {
    __shared__ float sred[4][32];
    __shared__ float sw1[27 * 52];   // k-stride 52 floats: spreads banks, <=2-way
    for (int i = threadIdx.x; i < 27 * 48; i += 256)
        sw1[(i / 48) * 52 + (i % 48)] = w1[i];
    __syncthreads();

    int blk = xcd_swz(blockIdx.x, (int)gridDim.x);
    int v = blk * (int)blockDim.x + (int)threadIdx.x;
    float acc[16];
    #pragma unroll
    for (int d = 0; d < 16; ++d) acc[d] = 0.f;
    if (v < N) {
        uint32_t cz = vo[v].x;
        int z = (int)(cz >> 22), y = (int)((cz >> 11) & 0x7FFu), x = (int)(cz & 0x7FFu);

        // self term (uniform weight pointer -> scalar loads; overlaps with probes)
        float4 f = ((const float4*)featp)[v];
        const float* wd = w1 + 13 * 48;
        #pragma unroll
        for (int d = 0; d < 16; ++d)
            acc[d] = fmaf(f.x, wd[d], fmaf(f.y, wd[16 + d], f.z * wd[32 + d]));

        // preload 6 bucket line0s (adjacent lanes share buckets -> few distinct lines)
        int yb0 = (y - 1) >> 1;
        uint4 q0[6];
        int bix[6], mm[6];
        #pragma unroll
        for (int p = 0; p < 6; ++p) {
            int zz = z + p / 2 - 1;
            int yb = yb0 + (p & 1);
            bool ok = ((unsigned)zz < SPARSE_D) & ((unsigned)yb < NYB);
            int b = ok ? (zz * NYB + yb) : 0;
            bix[p] = b;
            q0[p] = *(const uint4*)&bent2[(size_t)b * 32];
            mm[p] = ok ? 1 : 0;
        }

        uint32_t lpairs[PCAP];
        int cnt = 0;
        #pragma unroll
        for (int p = 0; p < 6; ++p) {
            int m = mm[p] ? min((int)q0[p].x, 31) : 0;
            int yb = yb0 + (p & 1);
            int dzk = (p / 2) * 9;
            auto scan_entry = [&](uint32_t e, int slot) {
                if (slot > m) return;
                int ey = (yb << 1) + (int)(e >> 29);
                int ex = (int)((e >> 18) & 0x7FFu);
                int dy = ey - y, dx = ex - x;
                if ((unsigned)(dy + 1) > 2u || (unsigned)(dx + 1) > 2u) return;
                uint32_t idx = e & 0x3FFFFu;
                if (idx == (uint32_t)v) return;
                int k = dzk + (dy + 1) * 3 + (dx + 1);
                if (cnt < PCAP) lpairs[cnt] = ((uint32_t)k << 18) | idx;
                ++cnt;
            };
            scan_entry(q0[p].y, 1);
            scan_entry(q0[p].z, 2);
            scan_entry(q0[p].w, 3);
            for (int w = 4; w <= m; w += 4) {
                uint4 q = *(const uint4*)&bent2[(size_t)bix[p] * 32 + w];
                scan_entry(q.x, w);
                scan_entry(q.y, w + 1);
                scan_entry(q.z, w + 2);
                scan_entry(q.w, w + 3);
            }
        }
        cnt = min(cnt, PCAP);
        pcnt[v] = cnt;
        for (int c = 0; c < cnt; ++c) {
            uint32_t pr = lpairs[c];
            pairs[(size_t)c * N + v] = pr;
            int k = (int)(pr >> 18), idx = (int)(pr & 0x3FFFFu);
            float4 g = ((const float4*)featp)[idx];     // idx near v -> L1/L2-resident lines
            const float* wk = &sw1[k * 52];
            #pragma unroll
            for (int d = 0; d < 16; ++d)
                acc[d] = fmaf(g.x, wk[d], fmaf(g.y, wk[16 + d], fmaf(g.z, wk[32 + d], acc[d])));
        }
        float4* o = (float4*)&h1[(size_t)v * 16];
        o[0] = make_float4(acc[0], acc[1], acc[2], acc[3]);
        o[1] = make_float4(acc[4], acc[5], acc[6], acc[7]);
        o[2] = make_float4(acc[8], acc[9], acc[10], acc[11]);
        o[3] = make_float4(acc[12], acc[13], acc[14], acc[15]);
    }
    stats_epilogue(acc, partials, blk, sred);
}

// ------- conv2 in SORTED order: LDS weights, BN1+ReLU on load, scatter-out via vo.y -------
__global__ void k_conv2(const float* __restrict__ h1, const int* __restrict__ pcnt,
                        const uint32_t* __restrict__ pairs, const float* __restrict__ w2,
                        const float* __restrict__ scsh1, const uint2* __restrict__ vo,
                        float* __restrict__ out, float* __restrict__ partials, int N) {
    __shared__ float sred[4][32];
    __shared__ float sc[16], sh[16];
    __shared__ float sw2[27 * 260];  // 28.1 KB; k-stride 260 -> ~2-way max aliasing
    if (threadIdx.x < 16) { sc[threadIdx.x] = scsh1[threadIdx.x]; sh[threadIdx.x] = scsh1[16 + threadIdx.x]; }
    for (int i = threadIdx.x; i < 27 * 256; i += 256)
        sw2[(i >> 8) * 260 + (i & 255)] = w2[i];
    __syncthreads();

    int blk = xcd_swz(blockIdx.x, (int)gridDim.x);
    int v = blk * (int)blockDim.x + (int)threadIdx.x;
    float acc[16];
    #pragma unroll
    for (int d = 0; d < 16; ++d) acc[d] = 0.f;
    if (v < N) {
        float g[16];
        #pragma unroll
        for (int c = 0; c < 16; c += 4) {
            float4 t = *(const float4*)&h1[(size_t)v * 16 + c];
            g[c]     = fmaxf(fmaf(t.x, sc[c],     sh[c]),     0.f);
            g[c + 1] = fmaxf(fmaf(t.y, sc[c + 1], sh[c + 1]), 0.f);
            g[c + 2] = fmaxf(fmaf(t.z, sc[c + 2], sh[c + 2]), 0.f);
            g[c + 3] = fmaxf(fmaf(t.w, sc[c + 3], sh[c + 3]), 0.f);
        }
        {
            const float* w = w2 + 13 * 256;    // uniform -> scalar-cache loads
            #pragma unroll
            for (int c = 0; c < 16; ++c)
                #pragma unroll
                for (int d = 0; d < 16; ++d)
                    acc[d] = fmaf(g[c], w[c * 16 + d], acc[d]);
        }
        int m = min(pcnt[v], PCAP);
        for (int cc = 0; cc < m; ++cc) {
            uint32_t pr = pairs[(size_t)cc * N + v];
            int k = (int)(pr >> 18), idx = (int)(pr & 0x3FFFFu);
            #pragma unroll
            for (int c = 0; c < 16; c += 4) {
                float4 t = *(const float4*)&h1[(size_t)idx * 16 + c];  // idx near v -> cache hits
                g[c]     = fmaxf(fmaf(t.x, sc[c],     sh[c]),     0.f);
                g[c + 1] = fmaxf(fmaf(t.y, sc[c + 1], sh[c + 1]), 0.f);
                g[c + 2] = fmaxf(fmaf(t.z, sc[c + 2], sh[c + 2]), 0.f);
                g[c + 3] = fmaxf(fmaf(t.w, sc[c + 3], sh[c + 3]), 0.f);
            }
            const float* wk = &sw2[k * 260];
            #pragma unroll
            for (int c = 0; c < 16; ++c)
                #pragma unroll
                for (int d = 0; d < 16; ++d)
                    acc[d] = fmaf(g[c], wk[c * 16 + d], acc[d]);
        }
        float4* o = (float4*)&out[(size_t)vo[v].y * 16];   // scatter store (fire-and-forget)
        o[0] = make_float4(acc[0], acc[1], acc[2], acc[3]);
        o[1] = make_float4(acc[4], acc[5], acc[6], acc[7]);
        o[2] = make_float4(acc[8], acc[9], acc[10], acc[11]);
        o[3] = make_float4(acc[12], acc[13], acc[14], acc[15]);
    }
    stats_epilogue(acc, partials, blk, sred);
}

// ------- finalize: 1024 threads, 32 row-groups x 32 channels, 4-way ILP -------
__global__ void k_finalize(const float* __restrict__ partials, int nb,
                           const float* __restrict__ gamma, const float* __restrict__ beta,
                           float* __restrict__ scsh, float invN) {
    __shared__ float red[32][33];
    int ch = threadIdx.x & 31;
    int rg = threadIdx.x >> 5;   // 0..31
    float s0 = 0.f, s1 = 0.f, s2 = 0.f, s3 = 0.f;
    int j = rg;
    for (; j + 96 < nb; j += 128) {
        s0 += partials[(size_t)(j      ) * 32 + ch];
        s1 += partials[(size_t)(j + 32 ) * 32 + ch];
        s2 += partials[(size_t)(j + 64 ) * 32 + ch];
        s3 += partials[(size_t)(j + 96 ) * 32 + ch];
    }
    for (; j < nb; j += 32) s0 += partials[(size_t)j * 32 + ch];
    red[rg][ch] = (s0 + s1) + (s2 + s3);
    __syncthreads();
    if (threadIdx.x < 32) {
        float t = 0.f;
        #pragma unroll
        for (int r = 0; r < 32; ++r) t += red[r][threadIdx.x];
        red[0][threadIdx.x] = t;
    }
    __syncthreads();
    if (threadIdx.x < 16) {
        int d = threadIdx.x;
        float mean = red[0][d] * invN;
        float var = red[0][16 + d] * invN - mean * mean;
        float s2c = gamma[d] * rsqrtf(var + BN_EPS);
        scsh[d] = s2c;
        scsh[16 + d] = beta[d] - mean * s2c;
    }
}

// ---------------- elementwise BN+ReLU (float4 per thread, orig order) ----------------
__global__ void k_bnrelu4(float* __restrict__ x, const float* __restrict__ scsh, int nvec) {
    __shared__ float sc[16], sh[16];
    if (threadIdx.x < 16) { sc[threadIdx.x] = scsh[threadIdx.x]; sh[threadIdx.x] = scsh[16 + threadIdx.x]; }
    __syncthreads();
    int i = blockIdx.x * blockDim.x + threadIdx.x;
    if (i < nvec) {
        float4 v = ((float4*)x)[i];
        int c0 = (i & 3) * 4;
        v.x = fmaxf(fmaf(v.x, sc[c0 + 0], sh[c0 + 0]), 0.f);
        v.y = fmaxf(fmaf(v.y, sc[c0 + 1], sh[c0 + 1]), 0.f);
        v.z = fmaxf(fmaf(v.z, sc[c0 + 2], sh[c0 + 2]), 0.f);
        v.w = fmaxf(fmaf(v.w, sc[c0 + 3], sh[c0 + 3]), 0.f);
        ((float4*)x)[i] = v;
    }
}

extern "C" void kernel_launch(void* const* d_in, const int* in_sizes, int n_in,
                              void* d_out, int out_size, void* d_ws, size_t ws_size,
                              hipStream_t stream) {
    const float* feat   = (const float*)d_in[0];
    const int*   coords = (const int*)d_in[1];
    const float* w1     = (const float*)d_in[2];
    const float* gamma1 = (const float*)d_in[3];
    const float* beta1  = (const float*)d_in[4];
    const float* w2     = (const float*)d_in[5];
    const float* gamma2 = (const float*)d_in[6];
    const float* beta2  = (const float*)d_in[7];
    float* out = (float*)d_out;
    const int N = in_sizes[0] / 3;

    const int T = 256;
    const int nb = (N + T - 1) / T;          // 782 blocks
    const int nvec = N * 16 / 4;
    const int nbv = (nvec + T - 1) / T;
    const float invN = 1.f / (float)N;

    // workspace layout (64B aligned)
    char* ws = (char*)d_ws;
    size_t off = 0;
    uint32_t* cnts  = (uint32_t*)(ws + off); off += ((size_t)NBUCKET * 4 + 63) & ~(size_t)63;  // 131KB
    int* base       = (int*)(ws + off);      off += ((size_t)(NBUCKET + 2) * 4 + 63) & ~(size_t)63;
    uint32_t* bent2 = (uint32_t*)(ws + off); off += (size_t)NBUCKET * 32 * 4;        // 4.2 MB
    uint32_t* slotarr = (uint32_t*)(ws + off); off += (size_t)N * 4;
    uint2* vo       = (uint2*)(ws + off);    off += (size_t)N * 8;
    int* pcnt       = (int*)(ws + off);      off += ((size_t)N * 4 + 63) & ~(size_t)63;
    uint32_t* pairs = (uint32_t*)(ws + off); off += (size_t)PCAP * N * 4;            // 9.6 MB
    float* h1       = (float*)(ws + off);    off += (size_t)N * 16 * 4;              // 12.8 MB
    float* featp    = (float*)(ws + off);    off += (size_t)N * 4 * 4;               // 3.2 MB
    float* partials = (float*)(ws + off);    off += ((size_t)nb * 32 * 4 + 63) & ~(size_t)63;
    float* stats    = (float*)(ws + off);    // [0:32] sc/sh 1, [32:64] sc/sh 2

    // 9 dispatches: memset, insert, scan1 (fused), permute, conv1, fin1, conv2, fin2, bnrelu
    hipMemsetAsync(cnts, 0, (size_t)NBUCKET * 4, stream);
    k_insert<<<nb, T, 0, stream>>>(coords, cnts, slotarr, N);
    k_scan1<<<NBS, T, 0, stream>>>(cnts, bent2, base, NBUCKET, NBS);
    k_permute<<<nb, T, 0, stream>>>(coords, feat, slotarr, base, bent2, vo, featp,
                                    NBUCKET, N);
    k_build_conv1<<<nb, T, 0, stream>>>(vo, bent2, featp, w1, pcnt, pairs, h1, partials, N);
    k_finalize<<<1, 1024, 0, stream>>>(partials, nb, gamma1, beta1, stats, invN);
    k_conv2<<<nb, T, 0, stream>>>(h1, pcnt, pairs, w2, stats, vo, out, partials, N);
    k_finalize<<<1, 1024, 0, stream>>>(partials, nb, gamma2, beta2, stats + 32, invN);
    k_bnrelu4<<<nbv, T, 0, stream>>>(out, stats + 32, nvec);
}

// Round 10
// 150.068 us; speedup vs baseline: 1.1309x; 1.1309x over previous
//
#include <hip/hip_runtime.h>
#include <stdint.h>

#define SPARSE_D 41
#define SPARSE_H 1600
#define SPARSE_W 1408
#define BN_EPS 0.001f

static constexpr int NYB = SPARSE_H / 2;          // 800
static constexpr int NBUCKET = SPARSE_D * NYB;    // 32,800
static constexpr int NBS = (NBUCKET + 255) / 256; // 129 scan blocks
static constexpr int PCAP = 12;                   // max non-self pairs per voxel (lambda~0.056)

// Spatial renumbering: voxels sorted by bucket (z*NYB + y/2) so adjacent threads
// are spatial neighbors -> gather instructions touch few distinct cache lines.
// bent2 bucket line: word0 = count, words 1..31 = entries (NEW idx).
// entry: [29]=y&1, [28:18]=x (11b), [17:0]=new idx ; pair: [22:18]=k, [17:0]=new idx
// vo[v] = (packed coords, original index)
// BN stats: conv epilogues atomicAdd 32 sums into p[blk%32][32] (4KB);
// consumers reduce the 4KB in their prologue (R5's 100KB version failed; 4KB is free).

// ---------------- pass 1: count per bucket, remember (bucket,slot) ----------------
__global__ void k_insert(const int* __restrict__ coords, uint32_t* __restrict__ cnts,
                         uint32_t* __restrict__ slotarr, int N) {
    int n = blockIdx.x * blockDim.x + threadIdx.x;
    if (n >= N) return;
    int4 c4 = ((const int4*)coords)[n];
    int z = c4.y, y = c4.z;
    int b = z * NYB + (y >> 1);
    int slot = (int)atomicAdd(&cnts[b], 1u) + 1;
    slotarr[n] = ((uint32_t)b << 6) | (uint32_t)min(slot, 32);   // 32 = overflow marker
}

// ---- pass 2a: per-block bucket-count sums (coalesced) + bent2 word0 scatter ----
__global__ void k_scanA(const uint32_t* __restrict__ cnts, uint32_t* __restrict__ bent2,
                        int* __restrict__ bsum, int NB) {
    __shared__ int ws[4];
    int b = blockIdx.x * 256 + threadIdx.x;
    int c = 0;
    if (b < NB) {
        uint32_t cv = cnts[b];
        bent2[(size_t)b * 32] = cv;      // count word (line-writes spread over 129 blocks)
        c = min((int)cv, 31);
    }
    int s = c;
    #pragma unroll
    for (int off = 32; off; off >>= 1) s += __shfl_xor(s, off);
    int lane = threadIdx.x & 63, wid = threadIdx.x >> 6;
    if (lane == 0) ws[wid] = s;
    __syncthreads();
    if (threadIdx.x == 0) bsum[blockIdx.x] = ws[0] + ws[1] + ws[2] + ws[3];
}

// ---- pass 2b: per-block redundant prefix of bsum + in-block scan -> base[b] ----
__global__ void k_scanC(const uint32_t* __restrict__ cnts, const int* __restrict__ bsum,
                        int* __restrict__ base, int NB, int nbs) {
    __shared__ int ws[4];
    __shared__ int wsum[4];
    __shared__ int s_pref;
    int tid = threadIdx.x, lane = tid & 63, wid = tid >> 6;

    // prefix over previous blocks (<=128 L2-hot loads, redundant per block)
    int pv = (tid < (int)blockIdx.x) ? bsum[tid] : 0;
    int ps = pv;
    #pragma unroll
    for (int off = 32; off; off >>= 1) ps += __shfl_xor(ps, off);
    if (lane == 0) ws[wid] = ps;
    __syncthreads();
    if (tid == 0) s_pref = ws[0] + ws[1] + ws[2] + ws[3];

    int b = blockIdx.x * 256 + tid;
    int c = (b < NB) ? min((int)cnts[b], 31) : 0;
    // wave inclusive scan
    int inc = c;
    #pragma unroll
    for (int off = 1; off < 64; off <<= 1) {
        int t = __shfl_up(inc, off);
        if (lane >= off) inc += t;
    }
    if (lane == 63) wsum[wid] = inc;
    __syncthreads();
    if (tid == 0) {
        int r = 0;
        #pragma unroll
        for (int w = 0; w < 4; ++w) { int t = wsum[w]; wsum[w] = r; r += t; }
    }
    __syncthreads();
    int excl = s_pref + wsum[wid] + inc - c;
    if (b < NB) base[b] = excl;                       // coalesced
    if ((int)blockIdx.x == nbs - 1 && tid == 255) {   // b >= NB here -> c = 0, excl = total
        base[NB] = excl;
        base[NB + 1] = 0;                             // overflow counter
    }
}

// ---------------- pass 3: build permutation + bucket entries + sorted feat ----------------
__global__ void k_permute(const int* __restrict__ coords, const float* __restrict__ feat,
                          const uint32_t* __restrict__ slotarr, int* __restrict__ base,
                          uint32_t* __restrict__ bent2, uint2* __restrict__ vo,
                          float* __restrict__ featp, int NB, int N) {
    int n = blockIdx.x * blockDim.x + threadIdx.x;
    if (n >= N) return;
    uint32_t sv = slotarr[n];
    int b = (int)(sv >> 6), s = (int)(sv & 63u);
    int4 c4 = ((const int4*)coords)[n];
    int z = c4.y, y = c4.z, x = c4.w;
    int v;
    if (s <= 31) {
        v = base[b] + s - 1;
        bent2[(size_t)b * 32 + s] = ((uint32_t)(y & 1) << 29) | ((uint32_t)x << 18) | (uint32_t)v;
    } else {
        v = base[NB] + atomicAdd((uint32_t*)&base[NB + 1], 1u);   // not in bucket (matches old drop)
    }
    uint32_t cz = ((uint32_t)z << 22) | ((uint32_t)y << 11) | (uint32_t)x;
    vo[v] = make_uint2(cz, (uint32_t)n);              // one 8B scattered store
    float f0 = feat[n * 3 + 0], f1 = feat[n * 3 + 1], f2 = feat[n * 3 + 2];
    ((float4*)featp)[v] = make_float4(f0, f1, f2, 0.f);
}

// XCD-chunked bijective block swizzle (adjacent blocks -> same XCD's L2)
__device__ __forceinline__ int xcd_swz(int o, int nwg) {
    int q = nwg >> 3, r = nwg & 7;
    int x = o & 7, i = o >> 3;
    return (x < r ? x * (q + 1) : r * (q + 1) + (x - r) * q) + i;
}

// ---- stats epilogue: wave shuffle reduce -> LDS -> atomicAdd into p[blk%32][32] ----
__device__ __forceinline__ void stats_epilogue(const float acc[16],
                                               float* __restrict__ p, int blk,
                                               float (*sred)[32]) {
    int lid = threadIdx.x & 63;
    int wid = threadIdx.x >> 6;
    #pragma unroll
    for (int d = 0; d < 16; ++d) {
        float v = acc[d];
        float v2 = v * v;
        #pragma unroll
        for (int off = 32; off; off >>= 1) {
            v += __shfl_xor(v, off);
            v2 += __shfl_xor(v2, off);
        }
        if (lid == 0) { sred[wid][d] = v; sred[wid][16 + d] = v2; }
    }
    __syncthreads();
    if (threadIdx.x < 32)
        atomicAdd(&p[((blk & 31) << 5) + threadIdx.x],
                  sred[0][threadIdx.x] + sred[1][threadIdx.x] +
                  sred[2][threadIdx.x] + sred[3][threadIdx.x]);
}

// ---- prologue: reduce p[32][32] (4KB, L2-hot) -> sc/sh in LDS. Ends with sync. ----
__device__ __forceinline__ void reduce32(const float* __restrict__ p,
                                         const float* __restrict__ gamma,
                                         const float* __restrict__ beta,
                                         float invN, float* __restrict__ sc,
                                         float* __restrict__ sh) {
    __shared__ float red[8][33];
    int ch = threadIdx.x & 31, rg = threadIdx.x >> 5;   // 8 groups x 4 rows each
    float s = p[(rg * 4 + 0) * 32 + ch] + p[(rg * 4 + 1) * 32 + ch] +
              p[(rg * 4 + 2) * 32 + ch] + p[(rg * 4 + 3) * 32 + ch];
    red[rg][ch] = s;
    __syncthreads();
    if (threadIdx.x < 32) {
        float t = 0.f;
        #pragma unroll
        for (int r = 0; r < 8; ++r) t += red[r][threadIdx.x];
        red[0][threadIdx.x] = t;   // column-exclusive
    }
    __syncthreads();
    if (threadIdx.x < 16) {
        int d = threadIdx.x;
        float mean = red[0][d] * invN;
        float var  = red[0][16 + d] * invN - mean * mean;
        float s2c  = gamma[d] * rsqrtf(var + BN_EPS);
        sc[d] = s2c;
        sh[d] = beta[d] - mean * s2c;
    }
    __syncthreads();
}

// ------ fused: build pairs + conv1 (C=3->16, LDS weights) in SORTED order ------
__global__ void k_build_conv1(const uint2* __restrict__ vo, const uint32_t* __restrict__ bent2,
                              const float* __restrict__ featp, const float* __restrict__ w1,
                              int* __restrict__ pcnt, uint32_t* __restrict__ pairs,
                              float* __restrict__ h1, float* __restrict__ p1, int N) {
    __shared__ float sred[4][32];
    __shared__ float sw1[27 * 52];   // k-stride 52 floats: spreads banks, <=2-way
    for (int i = threadIdx.x; i < 27 * 48; i += 256)
        sw1[(i / 48) * 52 + (i % 48)] = w1[i];
    __syncthreads();

    int blk = xcd_swz(blockIdx.x, (int)gridDim.x);
    int v = blk * (int)blockDim.x + (int)threadIdx.x;
    float acc[16];
    #pragma unroll
    for (int d = 0; d < 16; ++d) acc[d] = 0.f;
    if (v < N) {
        uint32_t cz = vo[v].x;
        int z = (int)(cz >> 22), y = (int)((cz >> 11) & 0x7FFu), x = (int)(cz & 0x7FFu);

        // self term (uniform weight pointer -> scalar loads; overlaps with probes)
        float4 f = ((const float4*)featp)[v];
        const float* wd = w1 + 13 * 48;
        #pragma unroll
        for (int d = 0; d < 16; ++d)
            acc[d] = fmaf(f.x, wd[d], fmaf(f.y, wd[16 + d], f.z * wd[32 + d]));

        // preload 6 bucket line0s (adjacent lanes share buckets -> few distinct lines)
        int yb0 = (y - 1) >> 1;
        uint4 q0[6];
        int bix[6], mm[6];
        #pragma unroll
        for (int p = 0; p < 6; ++p) {
            int zz = z + p / 2 - 1;
            int yb = yb0 + (p & 1);
            bool ok = ((unsigned)zz < SPARSE_D) & ((unsigned)yb < NYB);
            int b = ok ? (zz * NYB + yb) : 0;
            bix[p] = b;
            q0[p] = *(const uint4*)&bent2[(size_t)b * 32];
            mm[p] = ok ? 1 : 0;
        }

        uint32_t lpairs[PCAP];
        int cnt = 0;
        #pragma unroll
        for (int p = 0; p < 6; ++p) {
            int m = mm[p] ? min((int)q0[p].x, 31) : 0;
            int yb = yb0 + (p & 1);
            int dzk = (p / 2) * 9;
            auto scan_entry = [&](uint32_t e, int slot) {
                if (slot > m) return;
                int ey = (yb << 1) + (int)(e >> 29);
                int ex = (int)((e >> 18) & 0x7FFu);
                int dy = ey - y, dx = ex - x;
                if ((unsigned)(dy + 1) > 2u || (unsigned)(dx + 1) > 2u) return;
                uint32_t idx = e & 0x3FFFFu;
                if (idx == (uint32_t)v) return;
                int k = dzk + (dy + 1) * 3 + (dx + 1);
                if (cnt < PCAP) lpairs[cnt] = ((uint32_t)k << 18) | idx;
                ++cnt;
            };
            scan_entry(q0[p].y, 1);
            scan_entry(q0[p].z, 2);
            scan_entry(q0[p].w, 3);
            for (int w = 4; w <= m; w += 4) {
                uint4 q = *(const uint4*)&bent2[(size_t)bix[p] * 32 + w];
                scan_entry(q.x, w);
                scan_entry(q.y, w + 1);
                scan_entry(q.z, w + 2);
                scan_entry(q.w, w + 3);
            }
        }
        cnt = min(cnt, PCAP);
        pcnt[v] = cnt;
        for (int c = 0; c < cnt; ++c) {
            uint32_t pr = lpairs[c];
            pairs[(size_t)c * N + v] = pr;
            int k = (int)(pr >> 18), idx = (int)(pr & 0x3FFFFu);
            float4 g = ((const float4*)featp)[idx];     // idx near v -> L1/L2-resident lines
            const float* wk = &sw1[k * 52];
            #pragma unroll
            for (int d = 0; d < 16; ++d)
                acc[d] = fmaf(g.x, wk[d], fmaf(g.y, wk[16 + d], fmaf(g.z, wk[32 + d], acc[d])));
        }
        float4* o = (float4*)&h1[(size_t)v * 16];
        o[0] = make_float4(acc[0], acc[1], acc[2], acc[3]);
        o[1] = make_float4(acc[4], acc[5], acc[6], acc[7]);
        o[2] = make_float4(acc[8], acc[9], acc[10], acc[11]);
        o[3] = make_float4(acc[12], acc[13], acc[14], acc[15]);
    }
    stats_epilogue(acc, p1, blk, sred);
}

// ------- conv2: prologue BN1-reduce (4KB) + C=16->16 LDS weights + BN2 stats -------
__global__ void k_conv2(const float* __restrict__ h1, const int* __restrict__ pcnt,
                        const uint32_t* __restrict__ pairs, const float* __restrict__ w2,
                        const float* __restrict__ p1,
                        const float* __restrict__ gamma1, const float* __restrict__ beta1,
                        float invN, const uint2* __restrict__ vo,
                        float* __restrict__ out, float* __restrict__ p2, int N) {
    __shared__ float sred[4][32];
    __shared__ float sc[16], sh[16];
    __shared__ float sw2[27 * 260];  // 28.1 KB; k-stride 260 -> ~2-way max aliasing
    for (int i = threadIdx.x; i < 27 * 256; i += 256)
        sw2[(i >> 8) * 260 + (i & 255)] = w2[i];
    reduce32(p1, gamma1, beta1, invN, sc, sh);   // syncs inside cover sw2 too

    int blk = xcd_swz(blockIdx.x, (int)gridDim.x);
    int v = blk * (int)blockDim.x + (int)threadIdx.x;
    float acc[16];
    #pragma unroll
    for (int d = 0; d < 16; ++d) acc[d] = 0.f;
    if (v < N) {
        float g[16];
        #pragma unroll
        for (int c = 0; c < 16; c += 4) {
            float4 t = *(const float4*)&h1[(size_t)v * 16 + c];
            g[c]     = fmaxf(fmaf(t.x, sc[c],     sh[c]),     0.f);
            g[c + 1] = fmaxf(fmaf(t.y, sc[c + 1], sh[c + 1]), 0.f);
            g[c + 2] = fmaxf(fmaf(t.z, sc[c + 2], sh[c + 2]), 0.f);
            g[c + 3] = fmaxf(fmaf(t.w, sc[c + 3], sh[c + 3]), 0.f);
        }
        {
            const float* w = w2 + 13 * 256;    // uniform -> scalar-cache loads
            #pragma unroll
            for (int c = 0; c < 16; ++c)
                #pragma unroll
                for (int d = 0; d < 16; ++d)
                    acc[d] = fmaf(g[c], w[c * 16 + d], acc[d]);
        }
        int m = min(pcnt[v], PCAP);
        for (int cc = 0; cc < m; ++cc) {
            uint32_t pr = pairs[(size_t)cc * N + v];
            int k = (int)(pr >> 18), idx = (int)(pr & 0x3FFFFu);
            #pragma unroll
            for (int c = 0; c < 16; c += 4) {
                float4 t = *(const float4*)&h1[(size_t)idx * 16 + c];  // idx near v -> cache hits
                g[c]     = fmaxf(fmaf(t.x, sc[c],     sh[c]),     0.f);
                g[c + 1] = fmaxf(fmaf(t.y, sc[c + 1], sh[c + 1]), 0.f);
                g[c + 2] = fmaxf(fmaf(t.z, sc[c + 2], sh[c + 2]), 0.f);
                g[c + 3] = fmaxf(fmaf(t.w, sc[c + 3], sh[c + 3]), 0.f);
            }
            const float* wk = &sw2[k * 260];
            #pragma unroll
            for (int c = 0; c < 16; ++c)
                #pragma unroll
                for (int d = 0; d < 16; ++d)
                    acc[d] = fmaf(g[c], wk[c * 16 + d], acc[d]);
        }
        float4* o = (float4*)&out[(size_t)vo[v].y * 16];   // scatter store (fire-and-forget)
        o[0] = make_float4(acc[0], acc[1], acc[2], acc[3]);
        o[1] = make_float4(acc[4], acc[5], acc[6], acc[7]);
        o[2] = make_float4(acc[8], acc[9], acc[10], acc[11]);
        o[3] = make_float4(acc[12], acc[13], acc[14], acc[15]);
    }
    stats_epilogue(acc, p2, blk, sred);
}

// ------- bnrelu: prologue BN2-reduce (4KB) + grid-stride BN+ReLU on out -------
__global__ void k_bnrelu_fin(float* __restrict__ x, const float* __restrict__ p2,
                             const float* __restrict__ gamma2, const float* __restrict__ beta2,
                             float invN, int nvec) {
    __shared__ float sc[16], sh[16];
    reduce32(p2, gamma2, beta2, invN, sc, sh);
    int G = (int)gridDim.x * (int)blockDim.x;
    for (int i = blockIdx.x * blockDim.x + threadIdx.x; i < nvec; i += G) {
        float4 v = ((float4*)x)[i];
        int c0 = (i & 3) * 4;
        v.x = fmaxf(fmaf(v.x, sc[c0 + 0], sh[c0 + 0]), 0.f);
        v.y = fmaxf(fmaf(v.y, sc[c0 + 1], sh[c0 + 1]), 0.f);
        v.z = fmaxf(fmaf(v.z, sc[c0 + 2], sh[c0 + 2]), 0.f);
        v.w = fmaxf(fmaf(v.w, sc[c0 + 3], sh[c0 + 3]), 0.f);
        ((float4*)x)[i] = v;
    }
}

extern "C" void kernel_launch(void* const* d_in, const int* in_sizes, int n_in,
                              void* d_out, int out_size, void* d_ws, size_t ws_size,
                              hipStream_t stream) {
    const float* feat   = (const float*)d_in[0];
    const int*   coords = (const int*)d_in[1];
    const float* w1     = (const float*)d_in[2];
    const float* gamma1 = (const float*)d_in[3];
    const float* beta1  = (const float*)d_in[4];
    const float* w2     = (const float*)d_in[5];
    const float* gamma2 = (const float*)d_in[6];
    const float* beta2  = (const float*)d_in[7];
    float* out = (float*)d_out;
    const int N = in_sizes[0] / 3;

    const int T = 256;
    const int nb = (N + T - 1) / T;          // 782 blocks
    const int nvec = N * 16 / 4;
    const float invN = 1.f / (float)N;

    // workspace layout (64B aligned). cnts+p1+p2 contiguous -> single memset zeroes all.
    char* ws = (char*)d_ws;
    size_t off = 0;
    uint32_t* cnts  = (uint32_t*)(ws + off); off += (size_t)NBUCKET * 4;             // 131,200 B
    float* p1       = (float*)(ws + off);    off += 32 * 32 * 4;                     // 4 KB
    float* p2       = (float*)(ws + off);    off += 32 * 32 * 4;                     // 4 KB
    const size_t zbytes = off;               // zero region
    int* base       = (int*)(ws + off);      off += ((size_t)(NBUCKET + 2) * 4 + 63) & ~(size_t)63;
    int* bsum       = (int*)(ws + off);      off += ((size_t)NBS * 4 + 63) & ~(size_t)63;
    uint32_t* bent2 = (uint32_t*)(ws + off); off += (size_t)NBUCKET * 32 * 4;        // 4.2 MB
    uint32_t* slotarr = (uint32_t*)(ws + off); off += (size_t)N * 4;
    uint2* vo       = (uint2*)(ws + off);    off += (size_t)N * 8;
    int* pcnt       = (int*)(ws + off);      off += ((size_t)N * 4 + 63) & ~(size_t)63;
    uint32_t* pairs = (uint32_t*)(ws + off); off += (size_t)PCAP * N * 4;            // 9.6 MB
    float* h1       = (float*)(ws + off);    off += (size_t)N * 16 * 4;              // 12.8 MB
    float* featp    = (float*)(ws + off);    off += (size_t)N * 4 * 4;               // 3.2 MB

    // 8 dispatches: memset, insert, scanA, scanC, permute, conv1, conv2, bnrelu
    hipMemsetAsync(cnts, 0, zbytes, stream);
    k_insert<<<nb, T, 0, stream>>>(coords, cnts, slotarr, N);
    k_scanA<<<NBS, T, 0, stream>>>(cnts, bent2, bsum, NBUCKET);
    k_scanC<<<NBS, T, 0, stream>>>(cnts, bsum, base, NBUCKET, NBS);
    k_permute<<<nb, T, 0, stream>>>(coords, feat, slotarr, base, bent2, vo, featp,
                                    NBUCKET, N);
    k_build_conv1<<<nb, T, 0, stream>>>(vo, bent2, featp, w1, pcnt, pairs, h1, p1, N);
    k_conv2<<<nb, T, 0, stream>>>(h1, pcnt, pairs, w2, p1, gamma1, beta1, invN,
                                  vo, out, p2, N);
    k_bnrelu_fin<<<nb, T, 0, stream>>>(out, p2, gamma2, beta2, invN, nvec);
}